// Round 13
// baseline (171.070 us; speedup 1.0000x reference)
//
#include <hip/hip_runtime.h>

typedef unsigned short u16;
typedef __attribute__((ext_vector_type(8))) short short8;
typedef __attribute__((ext_vector_type(4))) float f32x4;

#define N_NODES 50000
#define C_ 128
#define E_ 10
#define NT_ 16
#define NBLK_MAIN 3136                           // >= 10 + 50000/16, multiple of 8
#define NBLK_S 196
#define K0_ 640
#define K1_ 512

// fragment-linear weight buffers (layout validated r3-r12):
// WF0: [E][8 col-sections][20 slots][64 lanes][8 elems] bf16  (slot = p*4+ks)
// WF1: [E][8 col-sections][16 slots][64 lanes][8 elems] bf16  (slot = q*4+ks)
#define WF0_BYTES (E_ * 8 * 20 * 512 * 2)
#define WF1_BYTES (E_ * 8 * 16 * 512 * 2)
#define CNT_OFF    (WF0_BYTES + WF1_BYTES)
#define BLKCNT_OFF (CNT_OFF + 64)
#define BASE_OFF   (BLKCNT_OFF + 8192)
#define LIST_OFF   (BASE_OFF + 8192)

__device__ __forceinline__ u16 f2bf(float f){ union{unsigned u; float f;} v; v.f = f; unsigned u = v.u; u += 0x7FFFu + ((u>>16)&1u); return (u16)(u>>16); }
__device__ __forceinline__ unsigned cvtpk(float a, float b){
    unsigned r;
    asm("v_cvt_pk_bf16_f32 %0, %1, %2" : "=v"(r) : "v"(a), "v"(b));
    return r;
}

// MFMA-based weight prep (validated r4-r12): grid = E_*9 blocks of 256 threads.
__global__ __launch_bounds__(256) void prep_weights_kernel(
    const float* __restrict__ tp2, const float* __restrict__ tp3,
    const float* __restrict__ c00, const float* __restrict__ c10, const float* __restrict__ c20,
    const float* __restrict__ c01, const float* __restrict__ c11, const float* __restrict__ c21,
    const float* __restrict__ lin0, const float* __restrict__ lin1,
    u16* __restrict__ WF0, u16* __restrict__ WF1)
{
    const int b = blockIdx.x;
    const int e = b / 9, kb = b % 9;
    const int which = (kb >= 5) ? 1 : 0;
    const int seg = which ? kb - 5 : kb;
    const float* __restrict__ lin = which ? lin1 : lin0;

    __shared__ u16 R[128 * 136];
    __shared__ u16 LT[128 * 132];

    const int tid = threadIdx.x;
    const float NC = 0.08838834764831845f;

    for (int t = tid; t < 128 * 32; t += 256) {
        const int jj = t >> 5, c4 = (t & 31) << 2;
        const float4 v = *(const float4*)(lin + jj * 128 + c4);
        LT[(c4 + 0) * 132 + jj] = f2bf(v.x * NC);
        LT[(c4 + 1) * 132 + jj] = f2bf(v.y * NC);
        LT[(c4 + 2) * 132 + jj] = f2bf(v.z * NC);
        LT[(c4 + 3) * 132 + jj] = f2bf(v.w * NC);
    }

    {
        const int c = tid >> 1, jh = (tid & 1) * 64;
        const float i128 = 0.08838834764831845f;
        const float i256 = 0.0625f;
        const float i512 = 0.04419417382415922f;
        const float I3   = 0.5773502691896258f;
        const float I9   = I3 * I3;
        const float t2_0 = tp2[0*C_+c], t2_1 = tp2[1*C_+c], t2_2 = tp2[2*C_+c], t2_3 = tp2[3*C_+c];
        const float t3_0 = tp3[0*C_+c], t3_1 = tp3[1*C_+c], t3_2 = tp3[2*C_+c];
        const float t3_3 = tp3[3*C_+c], t3_4 = tp3[4*C_+c], t3_5 = tp3[5*C_+c];
        const float t3_6 = tp3[6*C_+c], t3_7 = tp3[7*C_+c];

        const float* P0; const float* P1 = nullptr; const float* P2 = nullptr;
        float a0 = 0.f, a1 = 0.f, a2 = 0.f;
        if (!which) {
            const float* C0 = c00 + (size_t)e * C_   * C_;
            const float* C1 = c10 + (size_t)e * 2*C_ * C_;
            const float* C2 = c20 + (size_t)e * 4*C_ * C_;
            switch (seg) {
            case 0: P0 = C0 + c*C_;          a0 = i128; break;
            case 1: P0 = C1 + c*C_;          a0 = t2_0 * i256; break;
            case 2: P0 = C1 + (C_+c)*C_;     a0 = t2_3 * I3 * i256; break;
            case 3: P0 = C2 + c*C_;          a0 = t3_0 * t2_0 * i512; break;
            default:
                P0 = C2 + (C_+c)*C_;         a0 = t3_3 * t2_1 * I9 * i512;
                P1 = C2 + (2*C_+c)*C_;       a1 = t3_5 * t2_2 * I9 * i512;
                P2 = C2 + (3*C_+c)*C_;       a2 = t3_6 * t2_3 * I3 * i512; break;
            }
        } else {
            const float* C0 = c01 + (size_t)e * C_   * C_;
            const float* C1 = c11 + (size_t)e * 2*C_ * C_;
            const float* C2 = c21 + (size_t)e * 4*C_ * C_;
            switch (seg) {
            case 0: P0 = C0 + c*C_;          a0 = i128; break;
            case 1: P0 = C1 + c*C_;          a0 = t2_1 * I3 * i256;
                    P1 = C1 + (C_+c)*C_;     a1 = t2_2 * I3 * i256; break;
            case 2: P0 = C2 + c*C_;          a0 = t3_1 * t2_0 * I3 * i512;
                    P1 = C2 + (C_+c)*C_;     a1 = t3_2 * t2_1 * I9 * i512;
                    P2 = C2 + (2*C_+c)*C_;   a2 = t3_4 * t2_2 * I9 * i512; break;
            default: P0 = C2 + (3*C_+c)*C_;  a0 = t3_7 * t2_3 * I9 * i512; break;
            }
        }
        for (int j4 = 0; j4 < 64; j4 += 4) {
            const int jj = jh + j4;
            const float4 v = *(const float4*)(P0 + jj);
            float r0 = a0*v.x, r1 = a0*v.y, r2 = a0*v.z, r3 = a0*v.w;
            if (P1) {
                const float4 u = *(const float4*)(P1 + jj);
                r0 += a1*u.x; r1 += a1*u.y; r2 += a1*u.z; r3 += a1*u.w;
            }
            if (P2) {
                const float4 u = *(const float4*)(P2 + jj);
                r0 += a2*u.x; r1 += a2*u.y; r2 += a2*u.z; r3 += a2*u.w;
            }
            ushort4 st; st.x = f2bf(r0); st.y = f2bf(r1); st.z = f2bf(r2); st.w = f2bf(r3);
            *(ushort4*)&R[c * 136 + jj] = st;
        }
    }
    __syncthreads();

    const int wv = tid >> 6, l = tid & 63;
    const int lcol = l & 15, gD = l >> 4;
    f32x4 acc[2][8];
#pragma unroll
    for (int s = 0; s < 2; ++s)
#pragma unroll
        for (int t = 0; t < 8; ++t) acc[s][t] = (f32x4){0.f, 0.f, 0.f, 0.f};

#pragma unroll
    for (int ks2 = 0; ks2 < 4; ++ks2) {
        const int jj0 = ks2 * 32 + gD * 4;
        short8 bf[8];
#pragma unroll
        for (int t = 0; t < 8; ++t) {
            const int colB = t * 16 + lcol;
            union { unsigned long long q[2]; short8 v; } u;
            u.q[0] = *(const unsigned long long*)&LT[colB * 132 + jj0];
            u.q[1] = *(const unsigned long long*)&LT[colB * 132 + jj0 + 16];
            bf[t] = u.v;
        }
#pragma unroll
        for (int s = 0; s < 2; ++s) {
            const int krow = (wv + s * 4) * 16 + lcol;
            union { unsigned long long q[2]; short8 v; } ua;
            ua.q[0] = *(const unsigned long long*)&R[krow * 136 + jj0];
            ua.q[1] = *(const unsigned long long*)&R[krow * 136 + jj0 + 16];
#pragma unroll
            for (int t = 0; t < 8; ++t)
                acc[s][t] = __builtin_amdgcn_mfma_f32_16x16x32_bf16(ua.v, bf[t], acc[s][t], 0, 0, 0);
        }
    }

#pragma unroll
    for (int s = 0; s < 2; ++s) {
#pragma unroll
        for (int r = 0; r < 4; ++r) {
            const int k = (wv + s * 4) * 16 + 4 * gD + r;
            const int ks = k >> 5, r2 = k & 31;
            const int eh = r2 >> 4, g2 = (r2 >> 2) & 3, el = r2 & 3;
            const int elem = eh * 4 + el;
            const int lanef = lcol + 16 * g2;
            const int slot = seg * 4 + ks;
#pragma unroll
            for (int t = 0; t < 8; ++t) {
                const u16 wvl = f2bf(acc[s][t][r]);
                if (!which) WF0[(((size_t)(e*8 + t))*20 + slot)*512 + lanef*8 + elem] = wvl;
                else        WF1[(((size_t)(e*8 + t))*16 + slot)*512 + lanef*8 + elem] = wvl;
            }
        }
    }
}

// ---- deterministic stable counting sort (validated r8-r12) ----
__global__ void count_kernel(const float* __restrict__ attrs, int* __restrict__ blkcnt) {
    __shared__ int lcnt[E_];
    const int blk = blockIdx.x, tid = threadIdx.x;
    if (tid < E_) lcnt[tid] = 0;
    __syncthreads();
    const int n = blk * 256 + tid;
    if (n < N_NODES) {
        const float* a = attrs + (size_t)n * E_;
        int e = 0;
#pragma unroll
        for (int i = 0; i < E_; ++i) if (a[i] > 0.5f) e = i;
        atomicAdd(&lcnt[e], 1);
    }
    __syncthreads();
    if (tid < E_) blkcnt[tid * 200 + blk] = lcnt[tid];
}

__global__ void scan_kernel(const int* __restrict__ blkcnt, int* __restrict__ base,
                            int* __restrict__ cnt) {
    const int e = threadIdx.x;
    if (e < E_) {
        int acc = 0;
        for (int b = 0; b < NBLK_S; ++b) { base[e * 200 + b] = acc; acc += blkcnt[e * 200 + b]; }
        cnt[e] = acc;
    }
}

__global__ void scatter_kernel(const float* __restrict__ attrs, const int* __restrict__ base,
                               int* __restrict__ lists) {
    __shared__ int wcnt[4][E_];
    __shared__ int wbase[4][E_];
    const int blk = blockIdx.x, tid = threadIdx.x;
    const int wv = tid >> 6, lane = tid & 63;
    const int n = blk * 256 + tid;
    int e = -1;
    if (n < N_NODES) {
        e = 0;
        const float* a = attrs + (size_t)n * E_;
#pragma unroll
        for (int i = 0; i < E_; ++i) if (a[i] > 0.5f) e = i;
    }
    int rank = 0;
#pragma unroll
    for (int v = 0; v < E_; ++v) {
        const unsigned long long m = __ballot(e == v);
        if (e == v) rank = __popcll(m & ((1ull << lane) - 1ull));
        if (lane == 0) wcnt[wv][v] = __popcll(m);
    }
    __syncthreads();
    if (tid < E_) {
        int acc = 0;
#pragma unroll
        for (int w2 = 0; w2 < 4; ++w2) { wbase[w2][tid] = acc; acc += wcnt[w2][tid]; }
    }
    __syncthreads();
    if (n < N_NODES) lists[e * N_NODES + base[e * 200 + blk] + wbase[wv][e] + rank] = n;
}

// Main: 64-thread blocks = ONE wave, ZERO barriers. Wave owns 16 nodes x all
// 128 cols. Per k-chunk ks: load feats slice -> build 17 panels into wave-
// private LDS (in-wave lgkmcnt ordering only) -> slot-major MFMA: each
// A-fragment read ONCE (68 ds_read/tile), 8-deep B-load bursts feed acc[w].
// Waves run mutually desynchronized -> pipes overlap statistically.
__global__ __launch_bounds__(64) void main_kernel(
    const float* __restrict__ feats, const float* __restrict__ sc,
    const int* __restrict__ cnt, const int* __restrict__ lists,
    const u16* __restrict__ WF0, const u16* __restrict__ WF1,
    float* __restrict__ out)
{
    __shared__ __align__(16) u16 Abuf[17 * 512];   // 17,408 B (panels; reused as 8x516 f32 out-stage)
    __shared__ int nodes_s[16];

    const int l = threadIdx.x;                     // 0..63
    const int bxr = blockIdx.x;
    const int bx = (bxr & 7) * (NBLK_MAIN / 8) + (bxr >> 3);   // XCD-chunked, bijective

    int e = -1, tile = 0, accT = 0;
#pragma unroll
    for (int i = 0; i < E_; ++i) {
        const int ci = cnt[i];
        const int t = (ci + NT_ - 1) >> 4;
        if (e < 0 && bx < accT + t) { e = i; tile = bx - accT; }
        accT += t;
    }
    if (e < 0) return;
    const int nvalid = min(NT_, cnt[e] - tile * NT_);

    const int node = l >> 2, cq = l & 3;
    const int n = lists[e*N_NODES + tile*NT_ + (node < nvalid ? node : 0)];
    if (cq == 0) nodes_s[node] = n;

    // per-thread fragment write coordinates (validated bijection, no swizzle:
    // A-reads are lane-linear now -> conflict-free without it)
    const int gp  = (cq & 1) * 2;
    const int eh  = cq >> 1;
    const int off0u = (node + 16*gp)*8 + eh*4;     // u16 units within a 512-u16 slot
    const int off1u = off0u + 128;

    const int lcol = l & 15, g = l >> 4;
    const u16* WB0 = WF0 + ((size_t)(e*8)) * (20*512) + l*8;
    const u16* WB1 = WF1 + ((size_t)(e*8)) * (16*512) + l*8;

    f32x4 aS[8], aM0[8], aM1[8], aM2[8];
#pragma unroll
    for (int w = 0; w < 8; ++w) {
        aS[w] = (f32x4){0.f,0.f,0.f,0.f};
        aM0[w] = aS[w]; aM1[w] = aS[w]; aM2[w] = aS[w];
    }

#define WSLOT(P, V0,V1,V2,V3,V4,V5,V6,V7) do { \
        uint2 wa_, wb_; \
        wa_.x = cvtpk((V0),(V1)); wa_.y = cvtpk((V2),(V3)); \
        wb_.x = cvtpk((V4),(V5)); wb_.y = cvtpk((V6),(V7)); \
        *(uint2*)&Abuf[(P)*512 + off0u] = wa_; \
        *(uint2*)&Abuf[(P)*512 + off1u] = wb_; \
    } while (0)

    const float* fp = feats + (size_t)n * 512;

#pragma unroll
    for (int ks = 0; ks < 4; ++ks) {
        // ---- load this k-chunk's feats slice (channels ks*32 + cq*8 .. +8) ----
        const f32x4 s0 = *(const f32x4*)(fp + ks*32 + cq*8);
        const f32x4 s1 = *(const f32x4*)(fp + ks*32 + cq*8 + 4);
        f32x4 vv[6];
#pragma unroll
        for (int k = 0; k < 6; ++k)
            vv[k] = *(const f32x4*)(fp + 128 + ks*96 + cq*24 + 4*k);

        const float S[8]  = {s0.x,s0.y,s0.z,s0.w, s1.x,s1.y,s1.z,s1.w};
        const float V[24] = {vv[0].x,vv[0].y,vv[0].z,vv[0].w, vv[1].x,vv[1].y,vv[1].z,vv[1].w,
                             vv[2].x,vv[2].y,vv[2].z,vv[2].w, vv[3].x,vv[3].y,vv[3].z,vv[3].w,
                             vv[4].x,vv[4].y,vv[4].z,vv[4].w, vv[5].x,vv[5].y,vv[5].z,vv[5].w};
        float S2[8], VV[8];
#pragma unroll
        for (int i = 0; i < 8; ++i) {
            S2[i] = S[i]*S[i];
            VV[i] = V[3*i]*V[3*i] + V[3*i+1]*V[3*i+1] + V[3*i+2]*V[3*i+2];
        }

        // ---- build panels 0..4 (scalar) and 5..16 (vector q*3+m+5) ----
        WSLOT(0, S[0],S[1],S[2],S[3],S[4],S[5],S[6],S[7]);
        WSLOT(1, S2[0],S2[1],S2[2],S2[3],S2[4],S2[5],S2[6],S2[7]);
        WSLOT(2, VV[0],VV[1],VV[2],VV[3],VV[4],VV[5],VV[6],VV[7]);
        WSLOT(3, S2[0]*S[0],S2[1]*S[1],S2[2]*S[2],S2[3]*S[3],
                 S2[4]*S[4],S2[5]*S[5],S2[6]*S[6],S2[7]*S[7]);
        WSLOT(4, S[0]*VV[0],S[1]*VV[1],S[2]*VV[2],S[3]*VV[3],
                 S[4]*VV[4],S[5]*VV[5],S[6]*VV[6],S[7]*VV[7]);
#pragma unroll
        for (int m = 0; m < 3; ++m) {
            WSLOT(5+m,  V[0+m],V[3+m],V[6+m],V[9+m],V[12+m],V[15+m],V[18+m],V[21+m]);
            WSLOT(8+m,  S[0]*V[0+m],S[1]*V[3+m],S[2]*V[6+m],S[3]*V[9+m],
                        S[4]*V[12+m],S[5]*V[15+m],S[6]*V[18+m],S[7]*V[21+m]);
            WSLOT(11+m, S2[0]*V[0+m],S2[1]*V[3+m],S2[2]*V[6+m],S2[3]*V[9+m],
                        S2[4]*V[12+m],S2[5]*V[15+m],S2[6]*V[18+m],S2[7]*V[21+m]);
            WSLOT(14+m, VV[0]*V[0+m],VV[1]*V[3+m],VV[2]*V[6+m],VV[3]*V[9+m],
                        VV[4]*V[12+m],VV[5]*V[15+m],VV[6]*V[18+m],VV[7]*V[21+m]);
        }
        // (compiler inserts lgkmcnt before first A-read; same-wave so no barrier)

        // ---- scalar path: panel p, A read once, 8 B-loads burst ----
#pragma unroll
        for (int p = 0; p < 5; ++p) {
            const short8 a = *(const short8*)&Abuf[p*512 + l*8];
            short8 b[8];
#pragma unroll
            for (int w = 0; w < 8; ++w)
                b[w] = *(const short8*)(WB0 + (size_t)w*(20*512) + (p*4 + ks)*512);
#pragma unroll
            for (int w = 0; w < 8; ++w)
                aS[w] = __builtin_amdgcn_mfma_f32_16x16x32_bf16(a, b[w], aS[w], 0, 0, 0);
        }
        // ---- vector path: q, 3 A reads reused across 8 cols ----
#pragma unroll
        for (int q = 0; q < 4; ++q) {
            const short8 a0 = *(const short8*)&Abuf[(5 + q*3 + 0)*512 + l*8];
            const short8 a1 = *(const short8*)&Abuf[(5 + q*3 + 1)*512 + l*8];
            const short8 a2 = *(const short8*)&Abuf[(5 + q*3 + 2)*512 + l*8];
            short8 b[8];
#pragma unroll
            for (int w = 0; w < 8; ++w)
                b[w] = *(const short8*)(WB1 + (size_t)w*(16*512) + (q*4 + ks)*512);
#pragma unroll
            for (int w = 0; w < 8; ++w) {
                aM0[w] = __builtin_amdgcn_mfma_f32_16x16x32_bf16(a0, b[w], aM0[w], 0, 0, 0);
                aM1[w] = __builtin_amdgcn_mfma_f32_16x16x32_bf16(a1, b[w], aM1[w], 0, 0, 0);
                aM2[w] = __builtin_amdgcn_mfma_f32_16x16x32_bf16(a2, b[w], aM2[w], 0, 0, 0);
            }
        }
        // next ks overwrites Abuf; same-wave in-order LDS semantics keep it safe
    }

    // ---------- epilogue: 2 rounds of 8 nodes staged through Abuf ----------
    float* OutB = (float*)&Abuf[0];                // 8 x 516 floats = 16,512 B
#pragma unroll
    for (int h2 = 0; h2 < 2; ++h2) {
        if ((g >> 1) == h2) {
            const int gl = g & 1;
#pragma unroll
            for (int r = 0; r < 4; ++r) {
                float* ob = &OutB[(gl*4 + r)*516];
#pragma unroll
                for (int w = 0; w < 8; ++w) {
                    ob[w*16 + lcol] = aS[w][r];
                    ob[128 + 3*(w*16 + lcol) + 0] = aM0[w][r];
                    ob[128 + 3*(w*16 + lcol) + 1] = aM1[w][r];
                    ob[128 + 3*(w*16 + lcol) + 2] = aM2[w][r];
                }
            }
        }
        const int n8 = l >> 3;
        const int gidx = h2*8 + n8;
        const int nv2 = nodes_s[gidx];
        const bool v2 = gidx < nvalid;
        const size_t gb = (size_t)nv2 * 512;
#pragma unroll
        for (int j = 0; j < 16; ++j) {
            const int offf = j*32 + (l & 7)*4;
            const f32x4 vr = *(const f32x4*)&OutB[n8*516 + offf];
            const f32x4 s4 = *(const f32x4*)(sc + gb + offf);
            if (v2) *(f32x4*)(out + gb + offf) = vr + s4;
        }
    }
#undef WSLOT
}

extern "C" void kernel_launch(void* const* d_in, const int* in_sizes, int n_in,
                              void* d_out, int out_size, void* d_ws, size_t ws_size,
                              hipStream_t stream) {
    const float* feats = (const float*)d_in[0];
    const float* attrs = (const float*)d_in[1];
    const float* sc    = (const float*)d_in[2];
    const float* tp2   = (const float*)d_in[3];
    const float* tp3   = (const float*)d_in[4];
    const float* c00   = (const float*)d_in[5];
    const float* c01   = (const float*)d_in[6];
    const float* c10   = (const float*)d_in[7];
    const float* c11   = (const float*)d_in[8];
    const float* c20   = (const float*)d_in[9];
    const float* c21   = (const float*)d_in[10];
    const float* lin0  = (const float*)d_in[11];
    const float* lin1  = (const float*)d_in[12];
    float* out = (float*)d_out;

    char* ws = (char*)d_ws;
    u16* WF0    = (u16*)(ws);
    u16* WF1    = (u16*)(ws + WF0_BYTES);
    int* cnt    = (int*)(ws + CNT_OFF);
    int* blkcnt = (int*)(ws + BLKCNT_OFF);
    int* base   = (int*)(ws + BASE_OFF);
    int* lists  = (int*)(ws + LIST_OFF);

    hipLaunchKernelGGL(prep_weights_kernel, dim3(E_*9), dim3(256), 0, stream,
                       tp2, tp3, c00, c10, c20, c01, c11, c21, lin0, lin1, WF0, WF1);
    hipLaunchKernelGGL(count_kernel, dim3(NBLK_S), dim3(256), 0, stream, attrs, blkcnt);
    hipLaunchKernelGGL(scan_kernel, dim3(1), dim3(64), 0, stream, blkcnt, base, cnt);
    hipLaunchKernelGGL(scatter_kernel, dim3(NBLK_S), dim3(256), 0, stream, attrs, base, lists);
    hipLaunchKernelGGL(main_kernel, dim3(NBLK_MAIN), dim3(64), 0, stream,
                       feats, sc, cnt, lists, WF0, WF1, out);
}

// Round 14
// 111.971 us; speedup vs baseline: 1.5278x; 1.5278x over previous
//
#include <hip/hip_runtime.h>

typedef unsigned short u16;
typedef __attribute__((ext_vector_type(8))) short short8;
typedef __attribute__((ext_vector_type(4))) float f32x4;

#define N_NODES 50000
#define C_ 128
#define E_ 10
#define NT_ 32
#define NBLK_MAIN 1600                           // >= sum ceil(cnt_e/32) (max ~1573)
#define NBLK_S 196
#define K0_ 640
#define K1_ 512

// fragment-linear weight buffers (layout validated r3-r12):
// WF0: [E][8 col-sections][20 slots][64 lanes][8 elems] bf16  (slot = p*4+ks)
// WF1: [E][8 col-sections][16 slots][64 lanes][8 elems] bf16  (slot = q*4+ks)
#define WF0_BYTES (E_ * 8 * 20 * 512 * 2)
#define WF1_BYTES (E_ * 8 * 16 * 512 * 2)
#define CNT_OFF    (WF0_BYTES + WF1_BYTES)
#define BLKCNT_OFF (CNT_OFF + 64)
#define BASE_OFF   (BLKCNT_OFF + 8192)
#define LIST_OFF   (BASE_OFF + 8192)

__device__ __forceinline__ u16 f2bf(float f){ union{unsigned u; float f;} v; v.f = f; unsigned u = v.u; u += 0x7FFFu + ((u>>16)&1u); return (u16)(u>>16); }
__device__ __forceinline__ unsigned cvtpk(float a, float b){
    unsigned r;
    asm("v_cvt_pk_bf16_f32 %0, %1, %2" : "=v"(r) : "v"(a), "v"(b));
    return r;
}

// MFMA-based weight prep (validated r4-r12): grid = E_*9 blocks of 256 threads.
__global__ __launch_bounds__(256) void prep_weights_kernel(
    const float* __restrict__ tp2, const float* __restrict__ tp3,
    const float* __restrict__ c00, const float* __restrict__ c10, const float* __restrict__ c20,
    const float* __restrict__ c01, const float* __restrict__ c11, const float* __restrict__ c21,
    const float* __restrict__ lin0, const float* __restrict__ lin1,
    u16* __restrict__ WF0, u16* __restrict__ WF1)
{
    const int b = blockIdx.x;
    const int e = b / 9, kb = b % 9;
    const int which = (kb >= 5) ? 1 : 0;
    const int seg = which ? kb - 5 : kb;
    const float* __restrict__ lin = which ? lin1 : lin0;

    __shared__ u16 R[128 * 136];
    __shared__ u16 LT[128 * 132];

    const int tid = threadIdx.x;
    const float NC = 0.08838834764831845f;

    for (int t = tid; t < 128 * 32; t += 256) {
        const int jj = t >> 5, c4 = (t & 31) << 2;
        const float4 v = *(const float4*)(lin + jj * 128 + c4);
        LT[(c4 + 0) * 132 + jj] = f2bf(v.x * NC);
        LT[(c4 + 1) * 132 + jj] = f2bf(v.y * NC);
        LT[(c4 + 2) * 132 + jj] = f2bf(v.z * NC);
        LT[(c4 + 3) * 132 + jj] = f2bf(v.w * NC);
    }

    {
        const int c = tid >> 1, jh = (tid & 1) * 64;
        const float i128 = 0.08838834764831845f;
        const float i256 = 0.0625f;
        const float i512 = 0.04419417382415922f;
        const float I3   = 0.5773502691896258f;
        const float I9   = I3 * I3;
        const float t2_0 = tp2[0*C_+c], t2_1 = tp2[1*C_+c], t2_2 = tp2[2*C_+c], t2_3 = tp2[3*C_+c];
        const float t3_0 = tp3[0*C_+c], t3_1 = tp3[1*C_+c], t3_2 = tp3[2*C_+c];
        const float t3_3 = tp3[3*C_+c], t3_4 = tp3[4*C_+c], t3_5 = tp3[5*C_+c];
        const float t3_6 = tp3[6*C_+c], t3_7 = tp3[7*C_+c];

        const float* P0; const float* P1 = nullptr; const float* P2 = nullptr;
        float a0 = 0.f, a1 = 0.f, a2 = 0.f;
        if (!which) {
            const float* C0 = c00 + (size_t)e * C_   * C_;
            const float* C1 = c10 + (size_t)e * 2*C_ * C_;
            const float* C2 = c20 + (size_t)e * 4*C_ * C_;
            switch (seg) {
            case 0: P0 = C0 + c*C_;          a0 = i128; break;
            case 1: P0 = C1 + c*C_;          a0 = t2_0 * i256; break;
            case 2: P0 = C1 + (C_+c)*C_;     a0 = t2_3 * I3 * i256; break;
            case 3: P0 = C2 + c*C_;          a0 = t3_0 * t2_0 * i512; break;
            default:
                P0 = C2 + (C_+c)*C_;         a0 = t3_3 * t2_1 * I9 * i512;
                P1 = C2 + (2*C_+c)*C_;       a1 = t3_5 * t2_2 * I9 * i512;
                P2 = C2 + (3*C_+c)*C_;       a2 = t3_6 * t2_3 * I3 * i512; break;
            }
        } else {
            const float* C0 = c01 + (size_t)e * C_   * C_;
            const float* C1 = c11 + (size_t)e * 2*C_ * C_;
            const float* C2 = c21 + (size_t)e * 4*C_ * C_;
            switch (seg) {
            case 0: P0 = C0 + c*C_;          a0 = i128; break;
            case 1: P0 = C1 + c*C_;          a0 = t2_1 * I3 * i256;
                    P1 = C1 + (C_+c)*C_;     a1 = t2_2 * I3 * i256; break;
            case 2: P0 = C2 + c*C_;          a0 = t3_1 * t2_0 * I3 * i512;
                    P1 = C2 + (C_+c)*C_;     a1 = t3_2 * t2_1 * I9 * i512;
                    P2 = C2 + (2*C_+c)*C_;   a2 = t3_4 * t2_2 * I9 * i512; break;
            default: P0 = C2 + (3*C_+c)*C_;  a0 = t3_7 * t2_3 * I9 * i512; break;
            }
        }
        for (int j4 = 0; j4 < 64; j4 += 4) {
            const int jj = jh + j4;
            const float4 v = *(const float4*)(P0 + jj);
            float r0 = a0*v.x, r1 = a0*v.y, r2 = a0*v.z, r3 = a0*v.w;
            if (P1) {
                const float4 u = *(const float4*)(P1 + jj);
                r0 += a1*u.x; r1 += a1*u.y; r2 += a1*u.z; r3 += a1*u.w;
            }
            if (P2) {
                const float4 u = *(const float4*)(P2 + jj);
                r0 += a2*u.x; r1 += a2*u.y; r2 += a2*u.z; r3 += a2*u.w;
            }
            ushort4 st; st.x = f2bf(r0); st.y = f2bf(r1); st.z = f2bf(r2); st.w = f2bf(r3);
            *(ushort4*)&R[c * 136 + jj] = st;
        }
    }
    __syncthreads();

    const int wv = tid >> 6, l = tid & 63;
    const int lcol = l & 15, gD = l >> 4;
    f32x4 acc[2][8];
#pragma unroll
    for (int s = 0; s < 2; ++s)
#pragma unroll
        for (int t = 0; t < 8; ++t) acc[s][t] = (f32x4){0.f, 0.f, 0.f, 0.f};

#pragma unroll
    for (int ks2 = 0; ks2 < 4; ++ks2) {
        const int jj0 = ks2 * 32 + gD * 4;
        short8 bf[8];
#pragma unroll
        for (int t = 0; t < 8; ++t) {
            const int colB = t * 16 + lcol;
            union { unsigned long long q[2]; short8 v; } u;
            u.q[0] = *(const unsigned long long*)&LT[colB * 132 + jj0];
            u.q[1] = *(const unsigned long long*)&LT[colB * 132 + jj0 + 16];
            bf[t] = u.v;
        }
#pragma unroll
        for (int s = 0; s < 2; ++s) {
            const int krow = (wv + s * 4) * 16 + lcol;
            union { unsigned long long q[2]; short8 v; } ua;
            ua.q[0] = *(const unsigned long long*)&R[krow * 136 + jj0];
            ua.q[1] = *(const unsigned long long*)&R[krow * 136 + jj0 + 16];
#pragma unroll
            for (int t = 0; t < 8; ++t)
                acc[s][t] = __builtin_amdgcn_mfma_f32_16x16x32_bf16(ua.v, bf[t], acc[s][t], 0, 0, 0);
        }
    }

#pragma unroll
    for (int s = 0; s < 2; ++s) {
#pragma unroll
        for (int r = 0; r < 4; ++r) {
            const int k = (wv + s * 4) * 16 + 4 * gD + r;
            const int ks = k >> 5, r2 = k & 31;
            const int eh = r2 >> 4, g2 = (r2 >> 2) & 3, el = r2 & 3;
            const int elem = eh * 4 + el;
            const int lanef = lcol + 16 * g2;
            const int slot = seg * 4 + ks;
#pragma unroll
            for (int t = 0; t < 8; ++t) {
                const u16 wvl = f2bf(acc[s][t][r]);
                if (!which) WF0[(((size_t)(e*8 + t))*20 + slot)*512 + lanef*8 + elem] = wvl;
                else        WF1[(((size_t)(e*8 + t))*16 + slot)*512 + lanef*8 + elem] = wvl;
            }
        }
    }
}

// ---- deterministic stable counting sort (validated r8-r12) ----
__global__ void count_kernel(const float* __restrict__ attrs, int* __restrict__ blkcnt) {
    __shared__ int lcnt[E_];
    const int blk = blockIdx.x, tid = threadIdx.x;
    if (tid < E_) lcnt[tid] = 0;
    __syncthreads();
    const int n = blk * 256 + tid;
    if (n < N_NODES) {
        const float* a = attrs + (size_t)n * E_;
        int e = 0;
#pragma unroll
        for (int i = 0; i < E_; ++i) if (a[i] > 0.5f) e = i;
        atomicAdd(&lcnt[e], 1);
    }
    __syncthreads();
    if (tid < E_) blkcnt[tid * 200 + blk] = lcnt[tid];
}

__global__ void scan_kernel(const int* __restrict__ blkcnt, int* __restrict__ base,
                            int* __restrict__ cnt) {
    const int e = threadIdx.x;
    if (e < E_) {
        int acc = 0;
        for (int b = 0; b < NBLK_S; ++b) { base[e * 200 + b] = acc; acc += blkcnt[e * 200 + b]; }
        cnt[e] = acc;
    }
}

__global__ void scatter_kernel(const float* __restrict__ attrs, const int* __restrict__ base,
                               int* __restrict__ lists) {
    __shared__ int wcnt[4][E_];
    __shared__ int wbase[4][E_];
    const int blk = blockIdx.x, tid = threadIdx.x;
    const int wv = tid >> 6, lane = tid & 63;
    const int n = blk * 256 + tid;
    int e = -1;
    if (n < N_NODES) {
        e = 0;
        const float* a = attrs + (size_t)n * E_;
#pragma unroll
        for (int i = 0; i < E_; ++i) if (a[i] > 0.5f) e = i;
    }
    int rank = 0;
#pragma unroll
    for (int v = 0; v < E_; ++v) {
        const unsigned long long m = __ballot(e == v);
        if (e == v) rank = __popcll(m & ((1ull << lane) - 1ull));
        if (lane == 0) wcnt[wv][v] = __popcll(m);
    }
    __syncthreads();
    if (tid < E_) {
        int acc = 0;
#pragma unroll
        for (int w2 = 0; w2 < 4; ++w2) { wbase[w2][tid] = acc; acc += wcnt[w2][tid]; }
    }
    __syncthreads();
    if (n < N_NODES) lists[e * N_NODES + base[e * 200 + blk] + wbase[wv][e] + rank] = n;
}

// Main (best measured, r12): NT=32 sorted same-element nodes/block, 512 threads
// = 8 waves, each wave owns 16 cols and accumulates BOTH 16-node groups
// (B fragments reused 2x). Single 48 KB A buffer, strict build/MFMA alternation.
__global__ __launch_bounds__(512, 4) void main_kernel(
    const float* __restrict__ feats, const float* __restrict__ sc,
    const int* __restrict__ cnt, const int* __restrict__ lists,
    const u16* __restrict__ WF0, const u16* __restrict__ WF1,
    float* __restrict__ out)
{
    __shared__ __align__(16) u16 A[24 * 1024];   // 49,152 B (slot*1024 + h*512 + lane*8 + elem)

    const int tid = threadIdx.x;
    const int bxr = blockIdx.x;
    const int bx = (bxr & 7) * (NBLK_MAIN / 8) + (bxr >> 3);   // XCD-chunked, bijective

    int e = -1, tile = 0, accT = 0;
#pragma unroll
    for (int i = 0; i < E_; ++i) {
        const int ci = cnt[i];
        const int t = (ci + NT_ - 1) >> 5;
        if (e < 0 && bx < accT + t) { e = i; tile = bx - accT; }
        accT += t;
    }
    if (e < 0) return;
    const int nvalid = min(NT_, cnt[e] - tile * NT_);

    const int node = tid >> 4;          // 0..31
    const int cg   = tid & 15;          // 8 channels: c = cg*8 + i
    const int h    = node >> 4;         // node group 0/1
    const int nodeL = node & 15;
    const int n = (node < nvalid) ? lists[e*N_NODES + tile*NT_ + node] : -1;

    // ---------- load feats ----------
    float4 s0 = make_float4(0.f,0.f,0.f,0.f), s1 = s0;
    float4 v4[6];
#pragma unroll
    for (int k = 0; k < 6; ++k) v4[k] = s0;
    if (n >= 0) {
        const float* f = feats + (size_t)n * 512;
        s0 = *(const float4*)(f + cg*8);
        s1 = *(const float4*)(f + cg*8 + 4);
#pragma unroll
        for (int k = 0; k < 6; ++k) v4[k] = *(const float4*)(f + 128 + cg*24 + 4*k);
    }
    float S[8]  = {s0.x,s0.y,s0.z,s0.w, s1.x,s1.y,s1.z,s1.w};
    float V[24] = {v4[0].x,v4[0].y,v4[0].z,v4[0].w, v4[1].x,v4[1].y,v4[1].z,v4[1].w,
                   v4[2].x,v4[2].y,v4[2].z,v4[2].w, v4[3].x,v4[3].y,v4[3].z,v4[3].w,
                   v4[4].x,v4[4].y,v4[4].z,v4[4].w, v4[5].x,v4[5].y,v4[5].z,v4[5].w};
    float S2[8], VV[8];
#pragma unroll
    for (int i = 0; i < 8; ++i) {
        S2[i] = S[i]*S[i];
        VV[i] = V[3*i]*V[3*i] + V[3*i+1]*V[3*i+1] + V[3*i+2]*V[3*i+2];
    }

    // per-thread fragment coordinates (validated r7/r8 bijection, per node group)
    const int ksl = cg >> 2;
    const int eh  = (cg >> 1) & 1;
    const int gb  = (cg & 1) * 2;
    const int off0 = h*512 + (((nodeL + 16*gb)     ^ (ksl << 1)))*8 + 4*eh;
    const int off1 = h*512 + (((nodeL + 16*(gb+1)) ^ (ksl << 1)))*8 + 4*eh;

#define WSLOT(SLOT, V0,V1,V2,V3,V4,V5,V6,V7) do { \
        uint2 w0_, w1_; \
        w0_.x = cvtpk((V0),(V1)); w0_.y = cvtpk((V2),(V3)); \
        w1_.x = cvtpk((V4),(V5)); w1_.y = cvtpk((V6),(V7)); \
        *(uint2*)&A[(SLOT)*1024 + off0] = w0_; \
        *(uint2*)&A[(SLOT)*1024 + off1] = w1_; \
    } while (0)

    // MFMA-side coordinates: wave w owns 16 cols (section w)
    const int w = tid >> 6, l = tid & 63;
    const int lcol = l & 15, g = l >> 4;
    const int col = w*16 + lcol;
    const u16* WB0 = WF0 + ((size_t)(e*8 + w)) * (20*512) + l*8;
    const u16* WB1 = WF1 + ((size_t)(e*8 + w)) * (16*512) + l*8;

    f32x4 accS0 = {0.f,0.f,0.f,0.f}, accS1 = accS0;   // groups 0/1
    f32x4 aV[3][2];
#pragma unroll
    for (int m = 0; m < 3; ++m) { aV[m][0] = accS0; aV[m][1] = accS0; }

    // ---------- build0: scalar panels {S,S2,VV,S3,S*VV} ----------
    WSLOT(0*4 + ksl, S[0],S[1],S[2],S[3],S[4],S[5],S[6],S[7]);
    WSLOT(1*4 + ksl, S2[0],S2[1],S2[2],S2[3],S2[4],S2[5],S2[6],S2[7]);
    WSLOT(2*4 + ksl, VV[0],VV[1],VV[2],VV[3],VV[4],VV[5],VV[6],VV[7]);
    WSLOT(3*4 + ksl, S2[0]*S[0],S2[1]*S[1],S2[2]*S[2],S2[3]*S[3],
                     S2[4]*S[4],S2[5]*S[5],S2[6]*S[6],S2[7]*S[7]);
    WSLOT(4*4 + ksl, S[0]*VV[0],S[1]*VV[1],S[2]*VV[2],S[3]*VV[3],
                     S[4]*VV[4],S[5]*VV[5],S[6]*VV[6],S[7]*VV[7]);
    __syncthreads();

    // ---------- mfma0: scalar path, B reused for both groups ----------
#pragma unroll
    for (int ks2 = 0; ks2 < 4; ++ks2) {
        short8 bS[5];
#pragma unroll
        for (int p = 0; p < 5; ++p) bS[p] = *(const short8*)(WB0 + (p*4 + ks2)*512);
        const int lp8 = (l ^ (ks2 << 1)) * 8;
#pragma unroll
        for (int p = 0; p < 5; ++p) {
            const short8 a0 = *(const short8*)&A[(p*4 + ks2)*1024 + lp8];
            const short8 a1 = *(const short8*)&A[(p*4 + ks2)*1024 + 512 + lp8];
            accS0 = __builtin_amdgcn_mfma_f32_16x16x32_bf16(a0, bS[p], accS0, 0, 0, 0);
            accS1 = __builtin_amdgcn_mfma_f32_16x16x32_bf16(a1, bS[p], accS1, 0, 0, 0);
        }
    }
    __syncthreads();

    // ---------- build1: {Vm, S*Vm} (panels 0..5) ----------
#pragma unroll
    for (int m = 0; m < 3; ++m) {
        WSLOT(m*4 + ksl,     V[0+m],V[3+m],V[6+m],V[9+m],V[12+m],V[15+m],V[18+m],V[21+m]);
        WSLOT((3+m)*4 + ksl, S[0]*V[0+m],S[1]*V[3+m],S[2]*V[6+m],S[3]*V[9+m],
                             S[4]*V[12+m],S[5]*V[15+m],S[6]*V[18+m],S[7]*V[21+m]);
    }
    __syncthreads();

    // ---------- mfma1: vector q0/q1 ----------
#pragma unroll
    for (int ks2 = 0; ks2 < 4; ++ks2) {
        const short8 b0 = *(const short8*)(WB1 + (0*4 + ks2)*512);
        const short8 b1 = *(const short8*)(WB1 + (1*4 + ks2)*512);
        const int lp8 = (l ^ (ks2 << 1)) * 8;
#pragma unroll
        for (int q = 0; q < 2; ++q) {
            const short8 bb = q ? b1 : b0;
#pragma unroll
            for (int m = 0; m < 3; ++m) {
                const short8 a0 = *(const short8*)&A[((q*3 + m)*4 + ks2)*1024 + lp8];
                const short8 a1 = *(const short8*)&A[((q*3 + m)*4 + ks2)*1024 + 512 + lp8];
                aV[m][0] = __builtin_amdgcn_mfma_f32_16x16x32_bf16(a0, bb, aV[m][0], 0, 0, 0);
                aV[m][1] = __builtin_amdgcn_mfma_f32_16x16x32_bf16(a1, bb, aV[m][1], 0, 0, 0);
            }
        }
    }
    __syncthreads();

    // ---------- build2: {S2*Vm, VV*Vm} ----------
#pragma unroll
    for (int m = 0; m < 3; ++m) {
        WSLOT(m*4 + ksl,     S2[0]*V[0+m],S2[1]*V[3+m],S2[2]*V[6+m],S2[3]*V[9+m],
                             S2[4]*V[12+m],S2[5]*V[15+m],S2[6]*V[18+m],S2[7]*V[21+m]);
        WSLOT((3+m)*4 + ksl, VV[0]*V[0+m],VV[1]*V[3+m],VV[2]*V[6+m],VV[3]*V[9+m],
                             VV[4]*V[12+m],VV[5]*V[15+m],VV[6]*V[18+m],VV[7]*V[21+m]);
    }
    __syncthreads();

    // ---------- mfma2: vector q2/q3 ----------
#pragma unroll
    for (int ks2 = 0; ks2 < 4; ++ks2) {
        const short8 b2 = *(const short8*)(WB1 + (2*4 + ks2)*512);
        const short8 b3 = *(const short8*)(WB1 + (3*4 + ks2)*512);
        const int lp8 = (l ^ (ks2 << 1)) * 8;
#pragma unroll
        for (int q = 0; q < 2; ++q) {
            const short8 bb = q ? b3 : b2;
#pragma unroll
            for (int m = 0; m < 3; ++m) {
                const short8 a0 = *(const short8*)&A[((q*3 + m)*4 + ks2)*1024 + lp8];
                const short8 a1 = *(const short8*)&A[((q*3 + m)*4 + ks2)*1024 + 512 + lp8];
                aV[m][0] = __builtin_amdgcn_mfma_f32_16x16x32_bf16(a0, bb, aV[m][0], 0, 0, 0);
                aV[m][1] = __builtin_amdgcn_mfma_f32_16x16x32_bf16(a1, bb, aV[m][1], 0, 0, 0);
            }
        }
    }
    __syncthreads();

    // ---------- epilogue: stage + store, one 16-node group at a time ----------
    float* OutB = (float*)&A[0];       // 16 x 516 floats = 33,024 B

    // group 0
#pragma unroll
    for (int r = 0; r < 4; ++r) {
        const int nd = 4*g + r;
        OutB[nd*516 + col] = accS0[r];
#pragma unroll
        for (int m = 0; m < 3; ++m) OutB[nd*516 + 128 + 3*col + m] = aV[m][0][r];
    }
    __syncthreads();
    if (h == 0 && n >= 0) {
        const size_t gb2 = (size_t)n * 512 + cg * 4;
        const float* sp = sc + gb2;
#pragma unroll
        for (int j = 0; j < 8; ++j) {
            const f32x4 vres = *(const f32x4*)&OutB[nodeL*516 + cg*4 + 64*j];
            const f32x4 s4   = *(const f32x4*)(sp + 64*j);
            *(f32x4*)(out + gb2 + 64*j) = vres + s4;
        }
    }
    __syncthreads();

    // group 1
#pragma unroll
    for (int r = 0; r < 4; ++r) {
        const int nd = 4*g + r;
        OutB[nd*516 + col] = accS1[r];
#pragma unroll
        for (int m = 0; m < 3; ++m) OutB[nd*516 + 128 + 3*col + m] = aV[m][1][r];
    }
    __syncthreads();
    if (h == 1 && n >= 0) {
        const size_t gb2 = (size_t)n * 512 + cg * 4;
        const float* sp = sc + gb2;
#pragma unroll
        for (int j = 0; j < 8; ++j) {
            const f32x4 vres = *(const f32x4*)&OutB[nodeL*516 + cg*4 + 64*j];
            const f32x4 s4   = *(const f32x4*)(sp + 64*j);
            *(f32x4*)(out + gb2 + 64*j) = vres + s4;
        }
    }
#undef WSLOT
}

extern "C" void kernel_launch(void* const* d_in, const int* in_sizes, int n_in,
                              void* d_out, int out_size, void* d_ws, size_t ws_size,
                              hipStream_t stream) {
    const float* feats = (const float*)d_in[0];
    const float* attrs = (const float*)d_in[1];
    const float* sc    = (const float*)d_in[2];
    const float* tp2   = (const float*)d_in[3];
    const float* tp3   = (const float*)d_in[4];
    const float* c00   = (const float*)d_in[5];
    const float* c01   = (const float*)d_in[6];
    const float* c10   = (const float*)d_in[7];
    const float* c11   = (const float*)d_in[8];
    const float* c20   = (const float*)d_in[9];
    const float* c21   = (const float*)d_in[10];
    const float* lin0  = (const float*)d_in[11];
    const float* lin1  = (const float*)d_in[12];
    float* out = (float*)d_out;

    char* ws = (char*)d_ws;
    u16* WF0    = (u16*)(ws);
    u16* WF1    = (u16*)(ws + WF0_BYTES);
    int* cnt    = (int*)(ws + CNT_OFF);
    int* blkcnt = (int*)(ws + BLKCNT_OFF);
    int* base   = (int*)(ws + BASE_OFF);
    int* lists  = (int*)(ws + LIST_OFF);

    hipLaunchKernelGGL(prep_weights_kernel, dim3(E_*9), dim3(256), 0, stream,
                       tp2, tp3, c00, c10, c20, c01, c11, c21, lin0, lin1, WF0, WF1);
    hipLaunchKernelGGL(count_kernel, dim3(NBLK_S), dim3(256), 0, stream, attrs, blkcnt);
    hipLaunchKernelGGL(scan_kernel, dim3(1), dim3(64), 0, stream, blkcnt, base, cnt);
    hipLaunchKernelGGL(scatter_kernel, dim3(NBLK_S), dim3(256), 0, stream, attrs, base, lists);
    hipLaunchKernelGGL(main_kernel, dim3(NBLK_MAIN), dim3(512), 0, stream,
                       feats, sc, cnt, lists, WF0, WF1, out);
}